// Round 8
// baseline (1454.042 us; speedup 1.0000x reference)
//
#include <hip/hip_runtime.h>
#include <math.h>

typedef unsigned short ushort_t;
typedef unsigned int uint_t;
typedef __attribute__((ext_vector_type(8))) short bf16x8;
typedef __attribute__((ext_vector_type(4))) float f32x4;

#define NTOK 131072          // B*S
#define TM 16                // tokens per block
#define SROW 552             // A row stride bf16: 1104B row (16B aligned), 276dw==20 mod 32 -> <=4-way banks
#define SROW2 276            // dword stride
#define K0P 160              // layer0: [z(2),cond(128)] = 130, padded to 160
#define KHP 512              // hidden: h(512) exactly (te,pos folded into beff)
#define EPS 1e-5f

__device__ __forceinline__ ushort_t f2bf(float f) {
    uint_t x = __float_as_uint(f);
    x += 0x7FFFu + ((x >> 16) & 1u);   // RNE
    return (ushort_t)(x >> 16);
}
__device__ __forceinline__ float bf2f(ushort_t u) {
    return __uint_as_float(((uint_t)u) << 16);
}

#if defined(__has_builtin)
#  if __has_builtin(__builtin_amdgcn_cvt_pk_bf16_f32)
#    define HAVE_PK_BF16 1
#  endif
#endif
__device__ __forceinline__ uint_t pk_bf16(float a, float b) {
#ifdef HAVE_PK_BF16
    auto r = __builtin_amdgcn_cvt_pk_bf16_f32(a, b);
    union { decltype(r) v; uint_t u; } cv; cv.v = r;
    return cv.u;
#else
    return (uint_t)f2bf(a) | ((uint_t)f2bf(b) << 16);
#endif
}

// Wt storage row s = 64w+16j+c16  <->  feature n = 64w+4*c16+j  (interleaved tiles).
// k-order: new k maps to original W row k+2 (h / [z,cond] part); te,pos rows (orig 0,1) are folded into beff.
__global__ __launch_bounds__(256) void prep_w(const float* __restrict__ W,
                                              ushort_t* __restrict__ dst,
                                              int Kin, int Kpad) {
    int s   = blockIdx.x;              // 0..511
    int j   = (s >> 4) & 3;
    int c16 = s & 15;
    int n   = (s & ~63) + 4 * c16 + j;
    for (int k = threadIdx.x; k < Kpad; k += 256) {
        float v = (k < Kin) ? W[(k + 2) * 512 + n] : 0.0f;
        dst[s * Kpad + k] = f2bf(v);
    }
}

// beff[L][si][n] = b[n] + te*W[0][n] + pos(si)*W[1][n]
__global__ __launch_bounds__(512) void prep_bias(
    const float* __restrict__ t,
    const float* __restrict__ W0, const float* __restrict__ b0,
    const float* __restrict__ W1, const float* __restrict__ b1,
    const float* __restrict__ W2, const float* __restrict__ b2,
    float* __restrict__ beff)
{
    int L  = blockIdx.x >> 6;
    int si = blockIdx.x & 63;
    const float* W = (L == 0) ? W0 : (L == 1) ? W1 : W2;
    const float* b = (L == 0) ? b0 : (L == 1) ? b1 : b2;
    float te  = t[0];
    float pos = (float)(si + 1) * (1.0f / 64.0f);
    int n = threadIdx.x;
    beff[(L * 64 + si) * 512 + n] = b[n] + te * W[n] + pos * W[512 + n];
}

// One fused layer: 48x512 GEMM (primal + 2 tangents share B), beff bias, LN+softplus
// primal + LN/softplus JVP on tangents, packed-bf16 b64 write-back to A.
template<int KPAD>
__device__ __forceinline__ void do_layer(
    const ushort_t* __restrict__ Wt, const float* __restrict__ beffL,
    const float* __restrict__ gg, const float* __restrict__ bev,
    ushort_t* A_s, float (*stat)[6], int gm0)
{
    const int tid  = threadIdx.x;
    const int w    = tid >> 6;      // wave 0..7
    const int lane = tid & 63;
    const int q    = lane >> 4;     // quad 0..3
    const int c16  = lane & 15;
    const int nb   = w * 64;        // wave's 64-column base

    f32x4 acc[3][4];
#pragma unroll
    for (int m = 0; m < 3; m++)
#pragma unroll
        for (int j = 0; j < 4; j++) acc[m][j] = (f32x4){0.f, 0.f, 0.f, 0.f};

    const ushort_t* ap = A_s + c16 * SROW + q * 8;
    const ushort_t* bp = Wt + (nb + c16) * KPAD + q * 8;

    for (int ks = 0; ks < KPAD / 32; ks++) {
        bf16x8 af[3], bf[4];
#pragma unroll
        for (int m = 0; m < 3; m++)
            af[m] = *(const bf16x8*)(ap + m * 16 * SROW + ks * 32);
#pragma unroll
        for (int j = 0; j < 4; j++)
            bf[j] = *(const bf16x8*)(bp + j * 16 * KPAD + ks * 32);
#pragma unroll
        for (int m = 0; m < 3; m++)
#pragma unroll
            for (int j = 0; j < 4; j++)
                acc[m][j] = __builtin_amdgcn_mfma_f32_16x16x32_bf16(af[m], bf[j], acc[m][j], 0, 0, 0);
    }

    // per-token bias (te/pos folded): feature n = nb+4*c16+j -> float4
#pragma unroll
    for (int r = 0; r < 4; r++) {
        int si = (gm0 + 4 * q + r) & 63;
        f32x4 bv = *(const f32x4*)(beffL + si * 512 + nb + 4 * c16);
#pragma unroll
        for (int j = 0; j < 4; j++) acc[0][j][r] += bv[j];
    }

    // wave-local LN stats (6 sums per token over this wave's 64 cols)
    float st[4][6];
#pragma unroll
    for (int r = 0; r < 4; r++) {
        float s1 = 0.f, s2 = 0.f, a0 = 0.f, x0 = 0.f, a1 = 0.f, x1 = 0.f;
#pragma unroll
        for (int j = 0; j < 4; j++) {
            float p = acc[0][j][r], u0 = acc[1][j][r], u1 = acc[2][j][r];
            s1 += p; s2 += p * p;
            a0 += u0; x0 += p * u0;
            a1 += u1; x1 += p * u1;
        }
        st[r][0] = s1; st[r][1] = s2; st[r][2] = a0; st[r][3] = x0; st[r][4] = a1; st[r][5] = x1;
    }
#pragma unroll
    for (int d = 1; d <= 8; d <<= 1)
#pragma unroll
        for (int r = 0; r < 4; r++)
#pragma unroll
            for (int s = 0; s < 6; s++) st[r][s] += __shfl_xor(st[r][s], d);
    if (c16 == 0) {
#pragma unroll
        for (int r = 0; r < 4; r++)
#pragma unroll
            for (int s = 0; s < 6; s++)
                atomicAdd(&stat[4 * q + r][s], st[r][s]);
    }
    __syncthreads();   // stats complete; all K-loop reads of A done

    // epilogue: params recomputed per lane (cheap), softplus(LN)+JVP, packed b64 writes
    const f32x4 gv  = *(const f32x4*)(gg  + nb + 4 * c16);
    const f32x4 bvv = *(const f32x4*)(bev + nb + 4 * c16);
    const float inv = 1.0f / 512.0f;
#pragma unroll
    for (int r = 0; r < 4; r++) {
        const int tok = 4 * q + r;
        float s0 = stat[tok][0], s1 = stat[tok][1], s2 = stat[tok][2];
        float s3 = stat[tok][3], s4 = stat[tok][4], s5 = stat[tok][5];
        float mu  = s0 * inv;
        float var = s1 * inv - mu * mu;
        float rs  = rsqrtf(var + EPS);
        float dm0 = s2 * inv, dm1 = s4 * inv;
        float c0 = rs * (s3 * inv - mu * dm0);
        float c1 = rs * (s5 * inv - mu * dm1);

        float sp[4], d0[4], d1[4];
#pragma unroll
        for (int j = 0; j < 4; j++) {
            float p  = acc[0][j][r], u0 = acc[1][j][r], u1 = acc[2][j][r];
            float xh = (p - mu) * rs;
            float y  = fmaf(xh, gv[j], bvv[j]);
            float e  = __expf(-fabsf(y));
            float rinv = 1.0f / (1.0f + e);
            float sig  = (y >= 0.f) ? rinv : e * rinv;
            sp[j] = fmaxf(y, 0.f) + __logf(1.0f + e);
            float w0 = sig * gv[j] * rs;
            d0[j] = w0 * (u0 - fmaf(xh, c0, dm0));
            d1[j] = w0 * (u1 - fmaf(xh, c1, dm1));
        }
        const int col = nb + 4 * c16;   // 4 consecutive features -> aligned b64
        uint2 vx, v0, v1;
        vx.x = pk_bf16(sp[0], sp[1]); vx.y = pk_bf16(sp[2], sp[3]);
        v0.x = pk_bf16(d0[0], d0[1]); v0.y = pk_bf16(d0[2], d0[3]);
        v1.x = pk_bf16(d1[0], d1[1]); v1.y = pk_bf16(d1[2], d1[3]);
        *(uint2*)&A_s[tok * SROW + col]        = vx;
        *(uint2*)&A_s[(16 + tok) * SROW + col] = v0;
        *(uint2*)&A_s[(32 + tok) * SROW + col] = v1;
    }
    __syncthreads();   // A fully rewritten before next layer's K-loop
}

__global__ __launch_bounds__(512, 4) void ode_mfma(
    const float* __restrict__ t, const float* __restrict__ z, const float* __restrict__ cond,
    const ushort_t* __restrict__ Wt0, const ushort_t* __restrict__ Wt1, const ushort_t* __restrict__ Wt2,
    const float* __restrict__ beff,
    const float* __restrict__ g0, const float* __restrict__ be0,
    const float* __restrict__ g1, const float* __restrict__ be1,
    const float* __restrict__ g2, const float* __restrict__ be2,
    const float* __restrict__ W3, const float* __restrict__ b3,
    float* __restrict__ out)
{
    __shared__ ushort_t A_s[48 * SROW];       // rows 0..15 primal, 16..31 u0, 32..47 u1
    __shared__ float stat[3][TM][6];          // per-layer LN raw sums (LDS atomics)

    const int tid = threadIdx.x;
    const int gm0 = blockIdx.x * TM;
    uint_t* A32 = (uint_t*)A_s;

    // ---- zero phase ----
    if (tid < 3 * TM * 6) (&stat[0][0][0])[tid] = 0.f;
    for (int i = tid; i < 32 * 80; i += 512) {        // tangent rows 16..47, dw 0..79 (k 0..159)
        int row = 16 + i / 80, d = i % 80;
        A32[row * SROW2 + d] = 0u;
    }
    if (tid < 16 * 15) {                              // primal pad k 130..159 (dw 65..79)
        int row = tid / 15, d = 65 + tid % 15;
        A32[row * SROW2 + d] = 0u;
    }
    __syncthreads();

    // ---- fill phase: layer0 features [z(2), cond(128)] ----
    const float te = t[0];
    if (tid < TM) {
        int tok = tid, gm = gm0 + tok;
        A32[tok * SROW2 + 0] = pk_bf16(z[gm * 2 + 0], z[gm * 2 + 1]);
        A_s[(16 + tok) * SROW + 0] = (ushort_t)0x3F80;   // u0 = e_{z0}
        A_s[(32 + tok) * SROW + 1] = (ushort_t)0x3F80;   // u1 = e_{z1}
    }
    {
        int bi = gm0 >> 6;                               // 16 tokens share one batch row
        for (int i = tid; i < TM * 64; i += 512) {
            int tok = i >> 6, c2 = i & 63;
            const float2 cv = *(const float2*)&cond[bi * 128 + 2 * c2];
            A32[tok * SROW2 + 1 + c2] = pk_bf16(cv.x, cv.y);   // cols 2+2c2, 3+2c2
        }
    }
    __syncthreads();

    do_layer<K0P>(Wt0, beff + 0 * 64 * 512, g0, be0, A_s, stat[0], gm0);
    do_layer<KHP>(Wt1, beff + 1 * 64 * 512, g1, be1, A_s, stat[1], gm0);
    do_layer<KHP>(Wt2, beff + 2 * 64 * 512, g2, be2, A_s, stat[2], gm0);

    // ---- layer 3: h(512) @ W3[2:,:] + te/pos terms; z_dot + divergence ----
    {
        int tok = tid >> 5;       // 0..15
        int l32 = tid & 31;
        int gm  = gm0 + tok;
        const float2* W3v = (const float2*)W3;
        float a0 = 0.f, a1 = 0.f, d0 = 0.f, d1 = 0.f;
        for (int k = l32; k < 512; k += 32) {
            float2 wv = W3v[k + 2];
            float ax  = bf2f(A_s[tok * SROW + k]);
            float au0 = bf2f(A_s[(16 + tok) * SROW + k]);
            float au1 = bf2f(A_s[(32 + tok) * SROW + k]);
            a0 = fmaf(ax, wv.x, a0);
            a1 = fmaf(ax, wv.y, a1);
            d0 = fmaf(au0, wv.x, d0);
            d1 = fmaf(au1, wv.y, d1);
        }
#pragma unroll
        for (int d = 1; d <= 16; d <<= 1) {
            a0 += __shfl_xor(a0, d); a1 += __shfl_xor(a1, d);
            d0 += __shfl_xor(d0, d); d1 += __shfl_xor(d1, d);
        }
        if (l32 == 0) {
            float pos = (float)((gm & 63) + 1) * (1.0f / 64.0f);
            out[gm * 2 + 0]    = a0 + b3[0] + te * W3[0] + pos * W3[2];
            out[gm * 2 + 1]    = a1 + b3[1] + te * W3[1] + pos * W3[3];
            out[NTOK * 2 + gm] = -(d0 + d1);
        }
    }
}

extern "C" void kernel_launch(void* const* d_in, const int* in_sizes, int n_in,
                              void* d_out, int out_size, void* d_ws, size_t ws_size,
                              hipStream_t stream) {
    const float* t    = (const float*)d_in[0];
    const float* z    = (const float*)d_in[1];
    const float* cond = (const float*)d_in[2];
    const float* W0   = (const float*)d_in[3];
    const float* b0   = (const float*)d_in[4];
    const float* g0   = (const float*)d_in[5];
    const float* be0  = (const float*)d_in[6];
    const float* W1   = (const float*)d_in[7];
    const float* b1   = (const float*)d_in[8];
    const float* g1   = (const float*)d_in[9];
    const float* be1  = (const float*)d_in[10];
    const float* W2   = (const float*)d_in[11];
    const float* b2   = (const float*)d_in[12];
    const float* g2   = (const float*)d_in[13];
    const float* be2  = (const float*)d_in[14];
    const float* W3   = (const float*)d_in[15];
    const float* b3   = (const float*)d_in[16];
    float* out = (float*)d_out;

    ushort_t* Wt0 = (ushort_t*)d_ws;                    // 512*160
    ushort_t* Wt1 = Wt0 + 512 * K0P;                    // 512*512
    ushort_t* Wt2 = Wt1 + 512 * KHP;                    // 512*512
    float*    beff = (float*)(Wt2 + 512 * KHP);         // 3*64*512 fp32

    hipLaunchKernelGGL(prep_w, dim3(512), dim3(256), 0, stream, W0, Wt0, 130, K0P);
    hipLaunchKernelGGL(prep_w, dim3(512), dim3(256), 0, stream, W1, Wt1, 512, KHP);
    hipLaunchKernelGGL(prep_w, dim3(512), dim3(256), 0, stream, W2, Wt2, 512, KHP);
    hipLaunchKernelGGL(prep_bias, dim3(192), dim3(512), 0, stream,
                       t, W0, b0, W1, b1, W2, b2, beff);

    hipLaunchKernelGGL(ode_mfma, dim3(NTOK / TM), dim3(512), 0, stream,
                       t, z, cond, Wt0, Wt1, Wt2, beff,
                       g0, be0, g1, be1, g2, be2, W3, b3, out);
}